// Round 9
// baseline (314.757 us; speedup 1.0000x reference)
//
#include <hip/hip_runtime.h>
#include <hip/hip_cooperative_groups.h>
#include <math.h>

namespace cg = cooperative_groups;

#define FEAT 256
#define NB   16
#define TLEN 4096
#define NROWS (NB * TLEN)
#define GRID  512

// ws layout (element offsets, 4B elements)
#define OFF_BEFF  0                       // float
#define OFF_PART  2                       // float[8][1280] weff partials
#define OFF_ALPHA (OFF_PART + 8 * 1280)   // float[NB][TLEN]
#define OFF_W1    (OFF_ALPHA + NROWS)     // float[NB][TLEN]
#define OFF_W2    (OFF_W1 + NROWS)        // float[NB][TLEN]
#define OFF_FPOS  (OFF_W2 + NROWS)        // int[NB][TLEN]
#define OFF_NF    (OFF_FPOS + NROWS)      // int[NB]

#define PAD(t) ((t) + ((t) >> 4))

// One cooperative kernel, 4 phases separated by grid.sync():
//  P0: w_eff partials (blocks 0..39) + b_eff (block 40)
//  P1: per-block 128-timestep window: row-dots + z + sigmoid -> alpha
//  P2: per-batch f64 scan (blocks 0..15): w1/w2/fpos/n
//  P3: emit gather: 2048 waves x 8 rows
__global__ __launch_bounds__(256, 2) void cif_fused(
    const float* __restrict__ x, const float* __restrict__ conv_w,
    const float* __restrict__ conv_b, const float* __restrict__ lin_w,
    const float* __restrict__ lin_b, float* __restrict__ ws,
    float* __restrict__ out) {
  cg::grid_group grid = cg::this_grid();
  const int tid = threadIdx.x;
  const int bid = blockIdx.x;

  __shared__ double smem[2432];   // 19456 B, reused across phases

  // ---- P0: w_eff partial sums + b_eff ----
  if (bid < 40) {
    int ob = bid % 5, oc = bid / 5;
    int idx = ob * 256 + tid;            // idx = i*5 + k (coalesced over o-rows)
    float acc = 0.f;
    int o0 = oc * 32;
#pragma unroll 8
    for (int o = o0; o < o0 + 32; ++o)
      acc = fmaf(conv_w[o * (FEAT * 5) + idx], lin_w[o], acc);
    ws[OFF_PART + oc * 1280 + idx] = acc;
  } else if (bid == 40) {
    float* red = (float*)smem;
    red[tid] = conv_b[tid] * lin_w[tid];
    __syncthreads();
    for (int s = 128; s > 0; s >>= 1) {
      if (tid < s) red[tid] += red[tid + s];
      __syncthreads();
    }
    if (tid == 0) ws[OFF_BEFF] = red[0] + lin_b[0];
  }
  grid.sync();

  // ---- P1: fused row-dots + z + sigmoid -> alpha ----
  {
    float* sW = (float*)smem;            // 1280 floats: w_eff[k][i]
    float* sP = (float*)smem + 1280;     // 660 floats: P[k][local row]
#pragma unroll
    for (int j = 0; j < 5; ++j) {
      int idx = j * 256 + tid;
      float acc = 0.f;
#pragma unroll
      for (int c = 0; c < 8; ++c) acc += ws[OFF_PART + c * 1280 + idx];
      int i = idx / 5, k = idx - i * 5;
      sW[k * 256 + i] = acc;
    }
    const float b_eff = ws[OFF_BEFF];
    __syncthreads();

    const int t0 = bid * 128;
    const int bs = (t0 >> 12) << 12;     // batch start row
    const int be = bs + TLEN;            // batch end row
    const int lo = t0 - 2;               // local index base
    const int start = lo < bs ? bs : lo;
    const int end0  = t0 + 130;
    const int end   = end0 > be ? be : end0;
    const int cnt   = end - start;       // rows to dot (130 or 132)

    const int wave = tid >> 6, l = tid & 63, l8 = l & 7, g8 = l >> 3;
    float p[5][5];
#pragma unroll
    for (int rp = 0; rp < 5; ++rp)
#pragma unroll
      for (int k = 0; k < 5; ++k) p[rp][k] = 0.f;

    int j0 = wave * 8 + g8;
#pragma unroll
    for (int fp = 0; fp < 8; ++fp) {
      float4 w4[5];
#pragma unroll
      for (int k = 0; k < 5; ++k)
        w4[k] = *(const float4*)&sW[k * 256 + fp * 32 + l8 * 4];
#pragma unroll
      for (int rp = 0; rp < 5; ++rp) {
        int j = rp * 32 + j0;
        if (j < cnt) {
          float4 xv = *(const float4*)(x + (size_t)(start + j) * FEAT + fp * 32 + l8 * 4);
#pragma unroll
          for (int k = 0; k < 5; ++k)
            p[rp][k] = fmaf(xv.x, w4[k].x, fmaf(xv.y, w4[k].y,
                        fmaf(xv.z, w4[k].z, fmaf(xv.w, w4[k].w, p[rp][k]))));
        }
      }
    }
#pragma unroll
    for (int rp = 0; rp < 5; ++rp) {
      int j = rp * 32 + j0;
#pragma unroll
      for (int k = 0; k < 5; ++k) {
        p[rp][k] += __shfl_xor(p[rp][k], 1);
        p[rp][k] += __shfl_xor(p[rp][k], 2);
        p[rp][k] += __shfl_xor(p[rp][k], 4);
      }
      if (l8 == 0 && j < cnt) {
        int jl = (start + j) - lo;
#pragma unroll
        for (int k = 0; k < 5; ++k) sP[k * 132 + jl] = p[rp][k];
      }
    }
    __syncthreads();

    if (tid < 128) {
      int t = t0 + tid;
      float z = b_eff;
#pragma unroll
      for (int k = 0; k < 5; ++k) {
        int tt = t + k - 2;
        if (tt >= bs && tt < be) z += sP[k * 132 + (tt - lo)];
      }
      ws[OFF_ALPHA + t] = 1.f / (1.f + expf(-z));
    }
  }
  grid.sync();

  // ---- P2: per-batch f64 scan (blocks 0..15) ----
  if (bid < NB) {
    const int b = bid;
    float*  s_alpha = (float*)smem;      // PAD'd: 4351 floats (17404 B)
    double* s_part  = smem + 2176;       // 256 doubles at byte 17408
    for (int j = 0; j < 16; ++j) {
      int t = j * 256 + tid;
      s_alpha[PAD(t)] = ws[OFF_ALPHA + b * TLEN + t];
    }
    __syncthreads();
    const int base = tid * 16;
    double run = 0.0;
#pragma unroll
    for (int r = 0; r < 16; ++r) run += (double)s_alpha[PAD(base + r)];
    s_part[tid] = run;
    __syncthreads();
    for (int s = 1; s < 256; s <<= 1) {  // Hillis-Steele over 256 partials
      double add = (tid >= s) ? s_part[tid - s] : 0.0;
      __syncthreads();
      if (tid >= s) s_part[tid] += add;
      __syncthreads();
    }
    double offset = tid ? s_part[tid - 1] : 0.0;

    double Sprev = offset;
    double Fprev = floor(Sprev);
    double runl = 0.0;
    float* w1 = ws + OFF_W1 + b * TLEN;
    float* w2 = ws + OFF_W2 + b * TLEN;
    int* fpos = (int*)ws + OFF_FPOS + b * TLEN;
#pragma unroll
    for (int r = 0; r < 16; ++r) {
      int t = base + r;
      runl += (double)s_alpha[PAD(t)];
      double St = offset + runl;
      double Ft = floor(St);
      w1[t] = (float)(fmin(St, Fprev + 1.0) - Sprev);   // alpha_t, or a1 at fire
      if (Ft > Fprev) {
        w2[t] = (float)(St - Ft);                       // a2 -> next segment
        fpos[(int)Ft - 1] = t;                          // emission index F_t-1
      }
      Sprev = St; Fprev = Ft;
    }
    if (tid == 255) {
      int n = (int)Fprev;
      ((int*)ws)[OFF_NF + b] = n;
      out[(size_t)NROWS * FEAT + b] = (float)(n > 0 ? n : 1);   // len output
    }
  }
  grid.sync();

  // ---- P3: emit gather, one wave per output row, 8 rows/wave ----
  {
    const int lane = tid & 63;
    const int wave_id = bid * 4 + (tid >> 6);
    for (int r = 0; r < 8; ++r) {
      int row = wave_id * 8 + r;        // b*TLEN + j
      int b = row >> 12;
      int j = row & (TLEN - 1);
      int n = ((const int*)ws)[OFF_NF + b];
      int keep = n > 0 ? n : 1;
      float4 acc = make_float4(0.f, 0.f, 0.f, 0.f);
      if (j < keep) {
        const int* fpos = (const int*)ws + OFF_FPOS + b * TLEN;
        int t_lo = j ? fpos[j - 1] : 0;
        int t_hi = (j < n) ? fpos[j] : TLEN - 1;        // n==0: whole-seq hacc_f
        const float* w1 = ws + OFF_W1 + b * TLEN;
        const float* w2 = ws + OFF_W2 + b * TLEN;
        for (int t = t_lo; t <= t_hi; ++t) {
          float w = (j && t == t_lo) ? w2[t] : w1[t];
          float4 xv = *(const float4*)(x + ((size_t)b * TLEN + t) * FEAT + lane * 4);
          acc.x = fmaf(w, xv.x, acc.x);
          acc.y = fmaf(w, xv.y, acc.y);
          acc.z = fmaf(w, xv.z, acc.z);
          acc.w = fmaf(w, xv.w, acc.w);
        }
      }
      *(float4*)(out + (size_t)row * FEAT + lane * 4) = acc;
    }
  }
}

extern "C" void kernel_launch(void* const* d_in, const int* in_sizes, int n_in,
                              void* d_out, int out_size, void* d_ws, size_t ws_size,
                              hipStream_t stream) {
  const float* x      = (const float*)d_in[0];
  const float* conv_w = (const float*)d_in[1];
  const float* conv_b = (const float*)d_in[2];
  const float* lin_w  = (const float*)d_in[3];
  const float* lin_b  = (const float*)d_in[4];
  float* out = (float*)d_out;
  float* ws  = (float*)d_ws;

  void* args[] = {(void*)&x, (void*)&conv_w, (void*)&conv_b,
                  (void*)&lin_w, (void*)&lin_b, (void*)&ws, (void*)&out};
  hipLaunchCooperativeKernel((const void*)cif_fused, dim3(GRID), dim3(256),
                             args, 0, stream);
}

// Round 11
// 161.308 us; speedup vs baseline: 1.9513x; 1.9513x over previous
//
#include <hip/hip_runtime.h>
#include <math.h>

#define FEAT 256
#define NB   16
#define TLEN 4096
#define NROWS (NB * TLEN)
#define CHW   128                         // chunk width (timesteps per block)
#define NCH   (TLEN / CHW)                // 32 chunks per batch

// ws layout (element offsets, 4B elements)
#define OFF_WEFF  0                       // float[5][256]
#define OFF_BEFF  1280                    // float
#define OFF_PART  1282                    // float[8][1280] weff partials
#define OFF_ALPHA (OFF_PART + 8 * 1280)   // float[NROWS]
#define OFF_CS    (OFF_ALPHA + NROWS)     // double[NB*NCH] (77058*4 % 8 == 0)
#define OFF_W1    (OFF_CS + 2 * NB * NCH) // float[NROWS]
#define OFF_W2    (OFF_W1 + NROWS)        // float[NROWS]
#define OFF_FPOS  (OFF_W2 + NROWS)        // int[NB][TLEN]
#define OFF_NF    (OFF_FPOS + NROWS)      // int[NB]

// K1: 40 blocks of w_eff partial sums over 32-wide o-chunks.
__global__ __launch_bounds__(256) void weff1_kernel(
    const float* __restrict__ conv_w, const float* __restrict__ lin_w,
    float* __restrict__ ws) {
  int ob = blockIdx.x % 5, oc = blockIdx.x / 5;
  int idx = ob * 256 + threadIdx.x;      // idx = i*5 + k (coalesced over o-rows)
  float acc = 0.f;
  int o0 = oc * 32;
#pragma unroll 8
  for (int o = o0; o < o0 + 32; ++o)
    acc = fmaf(conv_w[o * (FEAT * 5) + idx], lin_w[o], acc);
  ws[OFF_PART + oc * 1280 + idx] = acc;
}

// K2: reduce 8 partials -> w_eff[k][i]; block 5 computes b_eff.
__global__ __launch_bounds__(256) void weff2_kernel(
    const float* __restrict__ conv_b, const float* __restrict__ lin_w,
    const float* __restrict__ lin_b, float* __restrict__ ws) {
  if (blockIdx.x < 5) {
    int idx = blockIdx.x * 256 + threadIdx.x;
    float acc = 0.f;
#pragma unroll
    for (int c = 0; c < 8; ++c) acc += ws[OFF_PART + c * 1280 + idx];
    int i = idx / 5, k = idx - i * 5;
    ws[OFF_WEFF + k * FEAT + i] = acc;
  } else {
    __shared__ float red[256];
    red[threadIdx.x] = conv_b[threadIdx.x] * lin_w[threadIdx.x];
    __syncthreads();
    for (int s = 128; s > 0; s >>= 1) {
      if (threadIdx.x < s) red[threadIdx.x] += red[threadIdx.x + s];
      __syncthreads();
    }
    if (threadIdx.x == 0) ws[OFF_BEFF] = red[0] + lin_b[0];
  }
}

// K3: fused row-dots + z + sigmoid + per-chunk f64 Hillis sum.
// Block = 128 timesteps; computes dots for its 130/132-row halo window
// (8-lane groups, 5 row-passes), alpha for its 128 steps, then a 128-wide
// f64 Hillis scan whose top element is published as this chunk's csum.
__global__ __launch_bounds__(256) void pdalpha_kernel(
    const float* __restrict__ x, float* __restrict__ ws) {
  __shared__ float  sW[5 * 256];   // w_eff[k][i]
  __shared__ float  sP[5 * 132];   // P[k][local row]
  __shared__ double sH[CHW];
  const int tid = threadIdx.x;

#pragma unroll
  for (int j = 0; j < 5; ++j) sW[j * 256 + tid] = ws[OFF_WEFF + j * 256 + tid];
  const float b_eff = ws[OFF_BEFF];
  __syncthreads();

  const int t0 = blockIdx.x * CHW;
  const int bs = t0 & ~(TLEN - 1);           // batch start row
  const int be = bs + TLEN;                  // batch end row
  const int lo = t0 - 2;                     // local index base
  const int start = lo < bs ? bs : lo;
  const int end0  = t0 + CHW + 2;
  const int end   = end0 > be ? be : end0;
  const int cnt   = end - start;             // 130 or 132 rows to dot

  const int wave = tid >> 6, l = tid & 63, l8 = l & 7, g8 = l >> 3;
  float p[5][5];
#pragma unroll
  for (int rp = 0; rp < 5; ++rp)
#pragma unroll
    for (int k = 0; k < 5; ++k) p[rp][k] = 0.f;

  int j0 = wave * 8 + g8;
#pragma unroll
  for (int fp = 0; fp < 8; ++fp) {
    float4 w4[5];
#pragma unroll
    for (int k = 0; k < 5; ++k)
      w4[k] = *(const float4*)&sW[k * 256 + fp * 32 + l8 * 4];
#pragma unroll
    for (int rp = 0; rp < 5; ++rp) {
      int j = rp * 32 + j0;
      if (j < cnt) {
        float4 xv = *(const float4*)(x + (size_t)(start + j) * FEAT + fp * 32 + l8 * 4);
#pragma unroll
        for (int k = 0; k < 5; ++k)
          p[rp][k] = fmaf(xv.x, w4[k].x, fmaf(xv.y, w4[k].y,
                      fmaf(xv.z, w4[k].z, fmaf(xv.w, w4[k].w, p[rp][k]))));
      }
    }
  }
#pragma unroll
  for (int rp = 0; rp < 5; ++rp) {
    int j = rp * 32 + j0;
#pragma unroll
    for (int k = 0; k < 5; ++k) {
      p[rp][k] += __shfl_xor(p[rp][k], 1);
      p[rp][k] += __shfl_xor(p[rp][k], 2);
      p[rp][k] += __shfl_xor(p[rp][k], 4);
    }
    if (l8 == 0 && j < cnt) {
      int jl = (start + j) - lo;
#pragma unroll
      for (int k = 0; k < 5; ++k) sP[k * 132 + jl] = p[rp][k];
    }
  }
  __syncthreads();

  if (tid < CHW) {
    int t = t0 + tid;
    float z = b_eff;
#pragma unroll
    for (int k = 0; k < 5; ++k) {
      int tt = t + k - 2;
      if (tt >= bs && tt < be) z += sP[k * 132 + (tt - lo)];
    }
    float a = 1.f / (1.f + expf(-z));
    ws[OFF_ALPHA + t] = a;
    sH[tid] = (double)a;
  }
  __syncthreads();
  for (int s = 1; s < CHW; s <<= 1) {        // 7-round Hillis over 128 f64
    double add = (tid >= s && tid < CHW) ? sH[tid - s] : 0.0;
    __syncthreads();
    if (tid >= s && tid < CHW) sH[tid] += add;
    __syncthreads();
  }
  if (tid == CHW - 1)
    ((double*)ws)[OFF_CS / 2 + blockIdx.x] = sH[CHW - 1];
}

// K4: per-chunk finalize.  offset = serial left-fold of csum[0..chunk)
// (its last op equals the producer's offset+csum exactly -> chunk-boundary
// bit-consistency); re-run the identical 128-wide Hillis; emit w1/w2/fpos.
__global__ __launch_bounds__(128) void scanB_kernel(
    float* __restrict__ ws, float* __restrict__ out) {
  const int bid = blockIdx.x;                // global chunk id
  const int b = bid >> 5, chunk = bid & (NCH - 1);
  const int tid = threadIdx.x;
  const int t = bid * CHW + tid;             // global row (== b*TLEN + local)
  const double* cs = (const double*)ws + OFF_CS / 2 + b * NCH;
  double offset = 0.0;
  for (int c = 0; c < chunk; ++c) offset += cs[c];

  __shared__ double sH[CHW];
  sH[tid] = (double)ws[OFF_ALPHA + t];
  __syncthreads();
  for (int s = 1; s < CHW; s <<= 1) {        // identical Hillis to K3
    double add = (tid >= s) ? sH[tid - s] : 0.0;
    __syncthreads();
    if (tid >= s) sH[tid] += add;
    __syncthreads();
  }
  double St = offset + sH[tid];
  double Sp = tid ? offset + sH[tid - 1] : offset;
  double Ft = floor(St), Fp = floor(Sp);

  ws[OFF_W1 + t] = (float)(fmin(St, Fp + 1.0) - Sp);   // alpha_t, or a1 at fire
  if (Ft > Fp) {
    ws[OFF_W2 + t] = (float)(St - Ft);                 // a2 -> next segment
    ((int*)ws)[OFF_FPOS + b * TLEN + (int)Ft - 1] = t - b * TLEN;  // local pos
  }
  if (chunk == NCH - 1 && tid == CHW - 1) {
    int n = (int)Ft;
    ((int*)ws)[OFF_NF + b] = n;
    out[(size_t)NROWS * FEAT + b] = (float)(n > 0 ? n : 1);        // len output
  }
}

// K5: one wave per output row j: gather weighted segment [t_lo..t_hi] of x;
// rows >= keep are zeros (d_out is poisoned).
__global__ __launch_bounds__(256) void emit_kernel(
    const float* __restrict__ x, const float* __restrict__ ws,
    float* __restrict__ out) {
  int gtid = blockIdx.x * 256 + threadIdx.x;
  int row  = gtid >> 6;          // b*TLEN + j
  int lane = gtid & 63;
  int b = row >> 12;
  int j = row & (TLEN - 1);
  int n = ((const int*)ws)[OFF_NF + b];
  int keep = n > 0 ? n : 1;
  float4 acc = make_float4(0.f, 0.f, 0.f, 0.f);
  if (j < keep) {
    const int* fpos = (const int*)ws + OFF_FPOS + b * TLEN;
    int t_lo = j ? fpos[j - 1] : 0;
    int t_hi = (j < n) ? fpos[j] : TLEN - 1;           // n==0: whole-seq hacc_f
    const float* w1 = ws + OFF_W1 + b * TLEN;
    const float* w2 = ws + OFF_W2 + b * TLEN;
    for (int t = t_lo; t <= t_hi; ++t) {
      float w = (j && t == t_lo) ? w2[t] : w1[t];
      float4 xv = *(const float4*)(x + ((size_t)b * TLEN + t) * FEAT + lane * 4);
      acc.x = fmaf(w, xv.x, acc.x);
      acc.y = fmaf(w, xv.y, acc.y);
      acc.z = fmaf(w, xv.z, acc.z);
      acc.w = fmaf(w, xv.w, acc.w);
    }
  }
  *(float4*)(out + (size_t)row * FEAT + lane * 4) = acc;
}

extern "C" void kernel_launch(void* const* d_in, const int* in_sizes, int n_in,
                              void* d_out, int out_size, void* d_ws, size_t ws_size,
                              hipStream_t stream) {
  const float* x      = (const float*)d_in[0];
  const float* conv_w = (const float*)d_in[1];
  const float* conv_b = (const float*)d_in[2];
  const float* lin_w  = (const float*)d_in[3];
  const float* lin_b  = (const float*)d_in[4];
  float* out = (float*)d_out;
  float* ws  = (float*)d_ws;

  hipLaunchKernelGGL(weff1_kernel, dim3(40), dim3(256), 0, stream,
                     conv_w, lin_w, ws);
  hipLaunchKernelGGL(weff2_kernel, dim3(6), dim3(256), 0, stream,
                     conv_b, lin_w, lin_b, ws);
  hipLaunchKernelGGL(pdalpha_kernel, dim3(NROWS / CHW), dim3(256), 0, stream, x, ws);
  hipLaunchKernelGGL(scanB_kernel, dim3(NROWS / CHW), dim3(128), 0, stream, ws, out);
  hipLaunchKernelGGL(emit_kernel, dim3(NROWS / 4), dim3(256), 0, stream, x, ws, out);
}

// Round 12
// 154.408 us; speedup vs baseline: 2.0385x; 1.0447x over previous
//
#include <hip/hip_runtime.h>
#include <math.h>

#define FEAT 256
#define NB   16
#define TLEN 4096
#define NROWS (NB * TLEN)

// ws layout (element offsets, 4B elements)
#define OFF_WEFF 0                        // float[5][256]
#define OFF_BEFF 1280                     // float
#define OFF_P    2048                     // float[5][NB][TLEN]
#define OFF_W1   (OFF_P + 5 * NROWS)      // float[NB][TLEN]
#define OFF_W2   (OFF_W1 + NROWS)         // float[NB][TLEN]
#define OFF_FPOS (OFF_W2 + NROWS)         // int[NB][TLEN]
#define OFF_NF   (OFF_FPOS + NROWS)       // int[NB]
#define OFF_PART (OFF_NF + 16)            // float[8][1280] weff partials
#define OFF_ALPHA (OFF_PART + 8 * 1280)   // float[NB][TLEN]
#define OFF_CSUM (OFF_ALPHA + NROWS)      // double[NB][16] (even float offset)

// Kernel A1: partial sums over o-chunks for w_eff.
__global__ __launch_bounds__(256) void weff1_kernel(
    const float* __restrict__ conv_w, const float* __restrict__ lin_w,
    float* __restrict__ ws) {
  int ob = blockIdx.x % 5, oc = blockIdx.x / 5;
  int idx = ob * 256 + threadIdx.x;      // idx = i*5 + k (coalesced over o-rows)
  float acc = 0.f;
  int o0 = oc * 32;
#pragma unroll 8
  for (int o = o0; o < o0 + 32; ++o)
    acc = fmaf(conv_w[o * (FEAT * 5) + idx], lin_w[o], acc);
  ws[OFF_PART + oc * 1280 + idx] = acc;
}

// Kernel A2: reduce 8 partials -> w_eff[k][i]; block 5 computes b_eff.
__global__ __launch_bounds__(256) void weff2_kernel(
    const float* __restrict__ conv_b, const float* __restrict__ lin_w,
    const float* __restrict__ lin_b, float* __restrict__ ws) {
  if (blockIdx.x < 5) {
    int idx = blockIdx.x * 256 + threadIdx.x;
    float acc = 0.f;
#pragma unroll
    for (int c = 0; c < 8; ++c) acc += ws[OFF_PART + c * 1280 + idx];
    int i = idx / 5, k = idx - i * 5;
    ws[OFF_WEFF + k * FEAT + i] = acc;
  } else {
    __shared__ float red[256];
    red[threadIdx.x] = conv_b[threadIdx.x] * lin_w[threadIdx.x];
    __syncthreads();
    for (int s = 128; s > 0; s >>= 1) {
      if (threadIdx.x < s) red[threadIdx.x] += red[threadIdx.x + s];
      __syncthreads();
    }
    if (threadIdx.x == 0) ws[OFF_BEFF] = red[0] + lin_b[0];
  }
}

// Kernel B: P[k][row] = dot(x[row,:], w_eff[k,:]).  8-lane groups own one
// row each; 3 shfl levels per k.
__global__ __launch_bounds__(256) void pdot_kernel(
    const float* __restrict__ x, float* __restrict__ ws) {
  int tid  = threadIdx.x;
  int wave = tid >> 6, l = tid & 63;
  int row  = blockIdx.x * 32 + wave * 8 + (l >> 3);
  int l8   = l & 7;
  const float* xr = x + (size_t)row * FEAT + l8 * 4;
  float p[5] = {0.f, 0.f, 0.f, 0.f, 0.f};
#pragma unroll
  for (int pass = 0; pass < 8; ++pass) {
    float4 xv = *(const float4*)(xr + pass * 32);
#pragma unroll
    for (int k = 0; k < 5; ++k) {
      float4 w4 = *(const float4*)(ws + OFF_WEFF + k * FEAT + pass * 32 + l8 * 4);
      p[k] = fmaf(xv.x, w4.x, fmaf(xv.y, w4.y,
              fmaf(xv.z, w4.z, fmaf(xv.w, w4.w, p[k]))));
    }
  }
#pragma unroll
  for (int k = 0; k < 5; ++k) {
    p[k] += __shfl_xor(p[k], 1);
    p[k] += __shfl_xor(p[k], 2);
    p[k] += __shfl_xor(p[k], 4);
  }
  if (l8 == 0) {
#pragma unroll
    for (int k = 0; k < 5; ++k) ws[OFF_P + (size_t)k * NROWS + row] = p[k];
  }
}

// Kernel C1: block = (batch b, chunk of 256 steps).  Compute alpha, scan it
// (Hillis-Steele f64), store alpha and the chunk total sS[255].  Using the
// Hillis result as the chunk sum makes scanB's S-sequence EXACTLY consistent
// across chunk boundaries (fires bijective with fpos writes).
__global__ __launch_bounds__(256) void scanA_kernel(float* __restrict__ ws) {
  const int b = blockIdx.x >> 4, chunk = blockIdx.x & 15;
  const int tid = threadIdx.x;
  const int t = chunk * 256 + tid;
  float z = ws[OFF_BEFF];
#pragma unroll
  for (int k = 0; k < 5; ++k) {
    int tt = t + k - 2;
    if (tt >= 0 && tt < TLEN) z += ws[OFF_P + (size_t)k * NROWS + b * TLEN + tt];
  }
  float a = 1.f / (1.f + expf(-z));
  ws[OFF_ALPHA + b * TLEN + t] = a;

  __shared__ double sS[256];
  sS[tid] = (double)a;
  __syncthreads();
  for (int s = 1; s < 256; s <<= 1) {
    double add = (tid >= s) ? sS[tid - s] : 0.0;
    __syncthreads();
    sS[tid] += add;
    __syncthreads();
  }
  if (tid == 255)
    ((double*)ws)[OFF_CSUM / 2 + b * 16 + chunk] = sS[255];
}

// Kernel C2: block = (b, chunk).  offset = serial left-fold of csum[0..chunk)
// (identical fold order in every block -> exact chunk-boundary consistency);
// Hillis-Steele scan of this chunk's 256 alphas; one thread per timestep
// emits w1/w2/fpos; last thread of last chunk emits n and the len output.
__global__ __launch_bounds__(256) void scanB_kernel(
    float* __restrict__ ws, float* __restrict__ out) {
  const int b = blockIdx.x >> 4, chunk = blockIdx.x & 15;
  const int tid = threadIdx.x;
  const int t = chunk * 256 + tid;
  const double* csum = (const double*)ws + OFF_CSUM / 2 + b * 16;
  double offset = 0.0;
  for (int c = 0; c < chunk; ++c) offset += csum[c];

  double a = (double)ws[OFF_ALPHA + b * TLEN + t];
  __shared__ double sS[256];
  sS[tid] = a;
  __syncthreads();
  for (int s = 1; s < 256; s <<= 1) {
    double add = (tid >= s) ? sS[tid - s] : 0.0;
    __syncthreads();
    sS[tid] += add;
    __syncthreads();
  }
  double St = offset + sS[tid];
  double Sp = tid ? offset + sS[tid - 1] : offset;   // == St of t-1, exactly
  double Ft = floor(St), Fp = floor(Sp);

  ws[OFF_W1 + b * TLEN + t] = (float)(fmin(St, Fp + 1.0) - Sp);  // alpha or a1
  if (Ft > Fp) {
    ws[OFF_W2 + b * TLEN + t] = (float)(St - Ft);                // a2
    ((int*)ws)[OFF_FPOS + b * TLEN + (int)Ft - 1] = t;           // fire pos
  }
  if (chunk == 15 && tid == 255) {
    int n = (int)Ft;
    ((int*)ws)[OFF_NF + b] = n;
    out[(size_t)NROWS * FEAT + b] = (float)(n > 0 ? n : 1);      // len output
  }
}

// Kernel D: one wave per output row j: gather weighted segment
// [t_lo..t_hi] of x; rows >= keep are zeros (d_out is poisoned).
__global__ __launch_bounds__(256) void emit_kernel(
    const float* __restrict__ x, const float* __restrict__ ws,
    float* __restrict__ out) {
  int gtid = blockIdx.x * 256 + threadIdx.x;
  int row  = gtid >> 6;          // b*TLEN + j
  int lane = gtid & 63;
  int b = row >> 12;
  int j = row & (TLEN - 1);
  int n = ((const int*)ws)[OFF_NF + b];
  int keep = n > 0 ? n : 1;
  float4 acc = make_float4(0.f, 0.f, 0.f, 0.f);
  if (j < keep) {
    const int* fpos = (const int*)ws + OFF_FPOS + b * TLEN;
    int t_lo = j ? fpos[j - 1] : 0;
    int t_hi = (j < n) ? fpos[j] : TLEN - 1;          // n==0: whole-seq hacc_f
    const float* w1 = ws + OFF_W1 + b * TLEN;
    const float* w2 = ws + OFF_W2 + b * TLEN;
    for (int t = t_lo; t <= t_hi; ++t) {
      float w = (j && t == t_lo) ? w2[t] : w1[t];
      float4 xv = *(const float4*)(x + ((size_t)b * TLEN + t) * FEAT + lane * 4);
      acc.x = fmaf(w, xv.x, acc.x);
      acc.y = fmaf(w, xv.y, acc.y);
      acc.z = fmaf(w, xv.z, acc.z);
      acc.w = fmaf(w, xv.w, acc.w);
    }
  }
  *(float4*)(out + (size_t)row * FEAT + lane * 4) = acc;
}

extern "C" void kernel_launch(void* const* d_in, const int* in_sizes, int n_in,
                              void* d_out, int out_size, void* d_ws, size_t ws_size,
                              hipStream_t stream) {
  const float* x      = (const float*)d_in[0];
  const float* conv_w = (const float*)d_in[1];
  const float* conv_b = (const float*)d_in[2];
  const float* lin_w  = (const float*)d_in[3];
  const float* lin_b  = (const float*)d_in[4];
  float* out = (float*)d_out;
  float* ws  = (float*)d_ws;

  hipLaunchKernelGGL(weff1_kernel, dim3(40), dim3(256), 0, stream,
                     conv_w, lin_w, ws);
  hipLaunchKernelGGL(weff2_kernel, dim3(6), dim3(256), 0, stream,
                     conv_b, lin_w, lin_b, ws);
  hipLaunchKernelGGL(pdot_kernel, dim3(NROWS / 32), dim3(256), 0, stream, x, ws);
  hipLaunchKernelGGL(scanA_kernel, dim3(NB * 16), dim3(256), 0, stream, ws);
  hipLaunchKernelGGL(scanB_kernel, dim3(NB * 16), dim3(256), 0, stream, ws, out);
  hipLaunchKernelGGL(emit_kernel, dim3(NROWS / 4), dim3(256), 0, stream, x, ws, out);
}